// Round 15
// baseline (292.865 us; speedup 1.0000x reference)
//
#include <hip/hip_runtime.h>
#include <cstddef>
#include <cstdint>

#define N_IN  128
#define N_HID 128
#define N_OUT 64
#define CHUNK 4096        // edges per countbin block
#define BSPAN 512         // nodes per bucket
#define SCAP  12288       // stage capacity per bucket (mean 8192, max~8650 @ E=800k)
#define HPAD  136         // Hs row pad (shorts): 272B rows -> 16B-aligned, 2-way banks

typedef unsigned short ushort;
typedef unsigned int uint;
using short8 = __attribute__((ext_vector_type(8))) short;
using f32x4  = __attribute__((ext_vector_type(4))) float;

__device__ __forceinline__ ushort f2b(float f) {
  uint u = __builtin_bit_cast(uint, f);
  uint r = (u + 0x7fffu + ((u >> 16) & 1u)) >> 16;   // RNE
  return (ushort)r;
}
__device__ __forceinline__ float b2f(ushort u) {
  return __builtin_bit_cast(float, ((uint)u) << 16);
}

// ================= fused bucket-bin + prep (no deg atomics — R13/R14) =================

__global__ __launch_bounds__(256) void countbin_kernel(
    const int* __restrict__ ei, int* __restrict__ gcur,
    uint* __restrict__ stage4, int E, int nbuck, int nch,
    const float* __restrict__ x, ushort* __restrict__ xb, int n4,
    const float* __restrict__ W1, ushort* __restrict__ pw1,
    const float* __restrict__ W2, ushort* __restrict__ pw2, int nb_cvt) {
  __shared__ int cnt[256], lstart[256], off[256], gbase[256];
  __shared__ uint stg[CHUNK];
  __shared__ unsigned char bos[CHUNK];
  int bid = blockIdx.x;
  if (bid >= nch) {
    int pb = bid - nch;
    if (pb < nb_cvt) {
      int i = pb * 256 + threadIdx.x;
      if (i >= n4) return;
      float4 v = reinterpret_cast<const float4*>(x)[i];
      ushort4 o;
      o.x = f2b(v.x); o.y = f2b(v.y); o.z = f2b(v.z); o.w = f2b(v.w);
      reinterpret_cast<ushort4*>(xb)[i] = o;
    } else if (pb < nb_cvt + 32) {
      constexpr int CT = N_HID / 16;
      int t = (pb - nb_cvt) * 256 + threadIdx.x;
      int lane = t & 63;
      int g = t >> 6;
      int ct = g % CT;
      int kk = (g / CT) % 4;
      int k  = g / (CT * 4);
      int col = ct * 16 + (lane & 15);
      int krow0 = kk * 32 + (lane >> 4) * 8;
      ushort* dst = pw1 + (size_t)t * 8;
      const float* src = W1 + ((size_t)k * 128 + krow0) * N_HID + col;
#pragma unroll
      for (int j = 0; j < 8; ++j) dst[j] = f2b(src[(size_t)j * N_HID]);
    } else {
      int t = (pb - nb_cvt - 32) * 256 + threadIdx.x;
      int lane = t & 63;
      int g = t >> 6;
      int ct = g & 15;
      int kk = g >> 4;
      int col = ct * 16 + (lane & 15);
      int kb = col >> 6;
      int cc = col & 63;
      int krow0 = kk * 32 + (lane >> 4) * 8;
      ushort* dst = pw2 + (size_t)t * 8;
#pragma unroll
      for (int j = 0; j < 8; ++j) {
        int r = krow0 + j;
        float w0 = W2[((size_t)0 * 128 + r) * 64 + cc];
        float w1 = W2[((size_t)1 * 128 + r) * 64 + cc];
        float w2 = W2[((size_t)2 * 128 + r) * 64 + cc];
        float w3 = W2[((size_t)3 * 128 + r) * 64 + cc];
        float v = (kb == 0) ? (w0 - w2)
                : (kb == 1) ? (w1 - 3.f * w3)
                : (kb == 2) ? (2.f * w2)
                            : (4.f * w3);
        dst[j] = f2b(v);
      }
    }
    return;
  }
  int e0 = bid * CHUNK;
  int tid = threadIdx.x;
  for (int i = tid; i < nbuck; i += 256) cnt[i] = 0;
  __syncthreads();
  int s[16], d[16];
#pragma unroll
  for (int j = 0; j < 16; ++j) {
    int e = e0 + tid + j * 256;
    s[j] = -1;
    if (e < E) {
      s[j] = ei[e];
      d[j] = ei[E + e];
      atomicAdd(&cnt[d[j] >> 9], 1);
    }
  }
  __syncthreads();
  if (tid == 0) {
    int run = 0;
    for (int b = 0; b < nbuck; ++b) { lstart[b] = run; run += cnt[b]; }
  }
  __syncthreads();
  for (int i = tid; i < nbuck; i += 256) off[i] = lstart[i];
  __syncthreads();
#pragma unroll
  for (int j = 0; j < 16; ++j) {
    if (s[j] >= 0) {
      int b = d[j] >> 9;
      int pos = atomicAdd(&off[b], 1);
      stg[pos] = (uint)s[j] | ((uint)(d[j] & (BSPAN - 1)) << 17);
      bos[pos] = (unsigned char)b;
    }
  }
  __syncthreads();
  for (int b = tid; b < nbuck; b += 256)
    if (cnt[b] > 0) gbase[b] = atomicAdd(&gcur[b], cnt[b]);
  __syncthreads();
  int total = min(CHUNK, E - e0);
  for (int i = tid; i < total; i += 256) {
    int b = bos[i];
    stage4[(size_t)b * SCAP + gbase[b] + (i - lstart[b])] = stg[i];
  }
}

// ================= binB2a: inline bucket-scan + per-bucket histogram -> rowptr, dis =================

__global__ __launch_bounds__(256) void binB2a_kernel(const uint* __restrict__ stage4,
                                                     const int* __restrict__ gcur,
                                                     int* __restrict__ rowptr,
                                                     float* __restrict__ dis,
                                                     int n, int nbuck, int E) {
  __shared__ int cnt[BSPAN];
  __shared__ int g[128];
  __shared__ int wsum[4];
  int b = blockIdx.x;
  int base = b << 9;
  int hi = min(base + BSPAN, n);
  int nb = hi - base;
  int tid = threadIdx.x;
  cnt[tid] = 0;
  cnt[tid + 256] = 0;
  for (int i = tid; i < nbuck; i += 256) g[i] = gcur[i];
  __syncthreads();
  int bb = 0;
  for (int i = 0; i < b; ++i) bb += g[i];   // LDS broadcast, <= 97 iters
  int cntb = g[b];
  const uint* st = stage4 + (size_t)b * SCAP;
  for (int t = tid; t < cntb; t += 256) atomicAdd(&cnt[st[t] >> 17], 1);
  __syncthreads();
  int c0 = cnt[2 * tid], c1 = cnt[2 * tid + 1];
  int pair = c0 + c1;
  int lane = tid & 63, wid = tid >> 6;
  int incl = pair;
#pragma unroll
  for (int off = 1; off < 64; off <<= 1) {
    int t = __shfl_up(incl, off, 64);
    if (lane >= off) incl += t;
  }
  if (lane == 63) wsum[wid] = incl;
  __syncthreads();
  int wbase = 0;
  for (int w = 0; w < wid; ++w) wbase += wsum[w];
  int e0 = bb + wbase + incl - pair;
  int l0 = 2 * tid, l1 = 2 * tid + 1;
  if (l0 < nb) {
    rowptr[base + l0] = e0;
    dis[base + l0] = (c0 > 0) ? rsqrtf((float)c0) : 0.f;
  }
  if (l1 < nb) {
    rowptr[base + l1] = e0 + c0;
    dis[base + l1] = (c1 > 0) ? rsqrtf((float)c1) : 0.f;
  }
  if (b == nbuck - 1 && tid == 0) rowptr[n] = E;
}

// ================= binB2b: fine scatter within bucket =================

__global__ __launch_bounds__(256) void binB2b_kernel(const uint* __restrict__ stage4,
                                                     const int* __restrict__ rowptr,
                                                     const int* __restrict__ gcur,
                                                     const float* __restrict__ dis,
                                                     int2* __restrict__ ew, int n) {
  __shared__ int cur[BSPAN];
  int b = blockIdx.x;
  int base = b << 9;
  int hi = min(base + BSPAN, n);
  for (int l = threadIdx.x; l < hi - base; l += 256) cur[l] = rowptr[base + l];
  __syncthreads();
  int cntb = gcur[b];
  const uint* st = stage4 + (size_t)b * SCAP;
  for (int t = threadIdx.x; t < cntb; t += 256) {
    uint v = st[t];
    int src = v & 0x1FFFF;
    int dl = v >> 17;
    int pos = atomicAdd(&cur[dl], 1);
    ew[pos] = make_int2(src, __builtin_bit_cast(int, dis[src]));
  }
}

// ================= sparse propagation, 128-wide (layer 1) =================
// 2 nodes/wave, 32 lanes x uint2; unroll 8 (unroll 16 measured WORSE, R11).

__global__ __launch_bounds__(256) void prop_kernel(
    const ushort* __restrict__ in, const ushort* __restrict__ sub,
    ushort* __restrict__ out,
    const int* __restrict__ rowptr, const int2* __restrict__ ew,
    const float* __restrict__ dis, int n) {
  int node = blockIdx.x * 8 + (threadIdx.x >> 5);
  if (node >= n) return;
  int hl = threadIdx.x & 31;
  int s = rowptr[node];
  int e = rowptr[node + 1];
  size_t ro = ((size_t)node << 7) + (hl << 2);
  uint2 sv = make_uint2(0u, 0u);
  if (sub != nullptr) sv = *reinterpret_cast<const uint2*>(sub + ro);
  float a0 = 0.f, a1 = 0.f, a2 = 0.f, a3 = 0.f;
  for (int i = s; i < e; i += 8) {
    int2 p[8];
#pragma unroll
    for (int j = 0; j < 8; ++j) {
      int idx = i + j;
      p[j] = ew[idx < e ? idx : e - 1];
    }
    uint2 v[8];
#pragma unroll
    for (int j = 0; j < 8; ++j)
      v[j] = *reinterpret_cast<const uint2*>(in + ((size_t)p[j].x << 7) + (hl << 2));
#pragma unroll
    for (int j = 0; j < 8; ++j) {
      float w = (i + j < e) ? __builtin_bit_cast(float, p[j].y) : 0.f;
      a0 = fmaf(w, b2f((ushort)v[j].x), a0);
      a1 = fmaf(w, b2f((ushort)(v[j].x >> 16)), a1);
      a2 = fmaf(w, b2f((ushort)v[j].y), a2);
      a3 = fmaf(w, b2f((ushort)(v[j].y >> 16)), a3);
    }
  }
  float sc = -dis[node];
  float r0, r1, r2, r3;
  if (sub != nullptr) {
    float t = 2.f * sc;
    r0 = fmaf(t, a0, -b2f((ushort)sv.x));
    r1 = fmaf(t, a1, -b2f((ushort)(sv.x >> 16)));
    r2 = fmaf(t, a2, -b2f((ushort)sv.y));
    r3 = fmaf(t, a3, -b2f((ushort)(sv.y >> 16)));
  } else {
    r0 = sc * a0; r1 = sc * a1; r2 = sc * a2; r3 = sc * a3;
  }
  uint2 o;
  o.x = (uint)f2b(r0) | ((uint)f2b(r1) << 16);
  o.y = (uint)f2b(r2) | ((uint)f2b(r3) << 16);
  *reinterpret_cast<uint2*>(out + ro) = o;
}

// ================= sparse propagation, 64-wide (layer-2 Horner chain) =================

template <bool F32OUT>
__global__ __launch_bounds__(256) void prop64_kernel(
    const ushort* __restrict__ in, const ushort* __restrict__ aux,
    void* __restrict__ outv,
    const int* __restrict__ rowptr, const int2* __restrict__ ew,
    const float* __restrict__ dis, const float* __restrict__ bias, int n) {
  int node = blockIdx.x * 16 + (threadIdx.x >> 4);
  if (node >= n) return;
  int fl = threadIdx.x & 15;
  int s = rowptr[node];
  int e = rowptr[node + 1];
  float a0 = 0.f, a1 = 0.f, a2 = 0.f, a3 = 0.f;
  for (int i = s; i < e; i += 8) {
    int2 p[8];
#pragma unroll
    for (int j = 0; j < 8; ++j) {
      int idx = i + j;
      p[j] = ew[idx < e ? idx : e - 1];
    }
    uint2 v[8];
#pragma unroll
    for (int j = 0; j < 8; ++j)
      v[j] = *reinterpret_cast<const uint2*>(in + ((size_t)p[j].x << 6) + (fl << 2));
#pragma unroll
    for (int j = 0; j < 8; ++j) {
      float w = (i + j < e) ? __builtin_bit_cast(float, p[j].y) : 0.f;
      a0 = fmaf(w, b2f((ushort)v[j].x), a0);
      a1 = fmaf(w, b2f((ushort)(v[j].x >> 16)), a1);
      a2 = fmaf(w, b2f((ushort)v[j].y), a2);
      a3 = fmaf(w, b2f((ushort)(v[j].y >> 16)), a3);
    }
  }
  float sc = -dis[node];
  size_t ro = ((size_t)node << 6) + (fl << 2);
  uint2 av = *reinterpret_cast<const uint2*>(aux + ro);
  float r0 = fmaf(sc, a0, b2f((ushort)av.x));
  float r1 = fmaf(sc, a1, b2f((ushort)(av.x >> 16)));
  float r2 = fmaf(sc, a2, b2f((ushort)av.y));
  float r3 = fmaf(sc, a3, b2f((ushort)(av.y >> 16)));
  if (F32OUT) {
    r0 += bias[fl << 2];
    r1 += bias[(fl << 2) + 1];
    r2 += bias[(fl << 2) + 2];
    r3 += bias[(fl << 2) + 3];
    float m = fmaxf(fmaxf(r0, r1), fmaxf(r2, r3));
#pragma unroll
    for (int o = 8; o > 0; o >>= 1) m = fmaxf(m, __shfl_xor(m, o, 64));
    float sum = __expf(r0 - m) + __expf(r1 - m) + __expf(r2 - m) + __expf(r3 - m);
#pragma unroll
    for (int o = 8; o > 0; o >>= 1) sum += __shfl_xor(sum, o, 64);
    float ls = logf(sum) + m;
    float4 o4 = make_float4(r0 - ls, r1 - ls, r2 - ls, r3 - ls);
    *reinterpret_cast<float4*>(reinterpret_cast<float*>(outv) + ro) = o4;
  } else {
    uint2 o;
    o.x = (uint)f2b(r0) | ((uint)f2b(r1) << 16);
    o.y = (uint)f2b(r2) | ((uint)f2b(r3) << 16);
    *reinterpret_cast<uint2*>(reinterpret_cast<ushort*>(outv) + ro) = o;
  }
}

// ================= fused layer-1 GEMM + Horner GEMM =================
// Part 1: H = relu([A0|A1|A2|A3] @ pw1 + b1) -> LDS tile (64 x 128, HPAD rows).
// Part 2: CB = H @ pw2 (K=128, 256 cols) straight from LDS. H never hits global.

__global__ __launch_bounds__(128) void mfma_gemm_fused_kernel(
    const ushort* __restrict__ A0, const ushort* __restrict__ A1,
    const ushort* __restrict__ A2, const ushort* __restrict__ A3,
    const ushort* __restrict__ pw1, const float* __restrict__ bias,
    const ushort* __restrict__ pw2, ushort* __restrict__ C, int n) {
  constexpr int CT = N_HID / 16;   // 8
  __shared__ ushort Hs[64][HPAD];
  int wid = threadIdx.x >> 6;
  int lane = threadIdx.x & 63;
  int rbase = (blockIdx.x * 2 + wid) * 32;
  // NOTE: no early return — all waves must reach __syncthreads (rbase<n guaranteed
  // for wid=0; wid=1 may exceed n only when n%64<=32; guard loads/stores instead).
  bool t0ok = rbase < n;
  bool t1ok = (rbase + 16) < n;
  const ushort* Ap[4] = {A0, A1, A2, A3};
  f32x4 acc[2][CT];
#pragma unroll
  for (int t = 0; t < 2; ++t)
#pragma unroll
    for (int c = 0; c < CT; ++c) acc[t][c] = (f32x4){0.f, 0.f, 0.f, 0.f};
  size_t aoff = (size_t)(rbase + (lane & 15)) * 128 + (lane >> 4) * 8;
#pragma unroll
  for (int k = 0; k < 4; ++k) {
    const ushort* A = Ap[k] + aoff;
#pragma unroll
    for (int kk = 0; kk < 4; ++kk) {
      short8 a0 = {};
      if (t0ok) a0 = *reinterpret_cast<const short8*>(A + kk * 32);
      short8 a1 = {};
      if (t1ok) a1 = *reinterpret_cast<const short8*>(A + 16 * 128 + kk * 32);
      const ushort* B = pw1 + ((size_t)((k * 4 + kk) * CT) * 64 + lane) * 8;
#pragma unroll
      for (int c = 0; c < CT; ++c) {
        short8 b = *reinterpret_cast<const short8*>(B + (size_t)c * 64 * 8);
        acc[0][c] = __builtin_amdgcn_mfma_f32_16x16x32_bf16(a0, b, acc[0][c], 0, 0, 0);
        acc[1][c] = __builtin_amdgcn_mfma_f32_16x16x32_bf16(a1, b, acc[1][c], 0, 0, 0);
      }
    }
  }
  int colb = lane & 15;
  int rsub = (lane >> 4) * 4;
  int lrow0 = wid * 32;
#pragma unroll
  for (int t = 0; t < 2; ++t) {
#pragma unroll
    for (int c = 0; c < CT; ++c) {
      int col = c * 16 + colb;
      float bv = bias[col];
#pragma unroll
      for (int r = 0; r < 4; ++r) {
        float v = fmaxf(acc[t][c][r] + bv, 0.f);
        Hs[lrow0 + t * 16 + rsub + r][col] = f2b(v);
      }
    }
  }
  __syncthreads();
  // ---- part 2: CB = Hs @ pw2, 256 cols, K=128 ----
#pragma unroll
  for (int t = 0; t < 2; ++t) {
    f32x4 acc2[16];
#pragma unroll
    for (int c = 0; c < 16; ++c) acc2[c] = (f32x4){0.f, 0.f, 0.f, 0.f};
    int rl = lrow0 + t * 16 + (lane & 15);
#pragma unroll
    for (int kk = 0; kk < 4; ++kk) {
      short8 a = *reinterpret_cast<const short8*>(&Hs[rl][kk * 32 + (lane >> 4) * 8]);
      const ushort* B = pw2 + ((size_t)(kk * 16) * 64 + lane) * 8;
#pragma unroll
      for (int c = 0; c < 16; ++c) {
        short8 b = *reinterpret_cast<const short8*>(B + (size_t)c * 64 * 8);
        acc2[c] = __builtin_amdgcn_mfma_f32_16x16x32_bf16(a, b, acc2[c], 0, 0, 0);
      }
    }
    int row0g = rbase + t * 16;
#pragma unroll
    for (int c = 0; c < 16; ++c) {
      int col = c * 16 + colb;
      int kb = col >> 6, wc = col & 63;
#pragma unroll
      for (int r = 0; r < 4; ++r) {
        int row = row0g + rsub + r;
        if (row < n) C[((size_t)kb * n + row) * 64 + wc] = f2b(acc2[c][r]);
      }
    }
  }
}

// ================= launcher =================

extern "C" void kernel_launch(void* const* d_in, const int* in_sizes, int n_in,
                              void* d_out, int out_size, void* d_ws, size_t ws_size,
                              hipStream_t stream) {
  const float* x  = (const float*)d_in[0];
  const int*   ei = (const int*)d_in[1];
  const float* W1 = (const float*)d_in[2];
  const float* b1 = (const float*)d_in[3];
  const float* W2 = (const float*)d_in[4];
  const float* b2 = (const float*)d_in[5];
  float* out = (float*)d_out;

  const int N = in_sizes[0] / N_IN;
  const int E = in_sizes[1] / 2;
  const int NBUCK = (N + BSPAN - 1) / BSPAN;
  const int NCH = (E + CHUNK - 1) / CHUNK;

  char* base = (char*)d_ws;
  size_t off = 0;
  auto alloc = [&](size_t bytes) -> void* {
    void* p = base + off;
    off = (off + bytes + 255) & ~(size_t)255;
    return p;
  };
  int*    gcur   = (int*)alloc((size_t)NBUCK * 4);
  int*    rowptr = (int*)alloc((size_t)(N + 1) * 4);
  uint*   stage4 = (uint*)alloc((size_t)NBUCK * SCAP * 4);
  int2*   ew     = (int2*)alloc((size_t)E * 8);
  float*  dis    = (float*)alloc((size_t)N * 4);
  size_t  fsz    = (size_t)N * N_IN * 2;
  ushort* S1 = (ushort*)alloc(fsz);
  ushort* S2 = (ushort*)alloc(fsz);
  ushort* S3 = (ushort*)alloc(fsz);
  ushort* S4 = (ushort*)alloc(fsz);
  ushort* CB = (ushort*)alloc((size_t)4 * N * N_OUT * 2);   // C0..C3, each [N,64]
  ushort* pw1 = (ushort*)alloc((size_t)4 * N_IN * N_HID * 2);
  ushort* pw2 = (ushort*)alloc((size_t)N_HID * 4 * N_OUT * 2);

  ushort *xb = S1, *T1 = S2, *T2 = S3, *T3 = S4;
  ushort *I2 = S2, *I3 = S3;            // layer-2 chain reuses T1/T2 regions
  ushort *C0 = CB, *C1 = CB + (size_t)N * 64, *C2 = CB + (size_t)2 * N * 64,
         *C3 = CB + (size_t)3 * N * 64;

  int n4 = N * N_IN / 4;
  int nb_cvt = (n4 + 255) / 256;

  hipMemsetAsync(gcur, 0, (size_t)NBUCK * 4, stream);
  countbin_kernel<<<NCH + nb_cvt + 32 + 16, 256, 0, stream>>>(
      ei, gcur, stage4, E, NBUCK, NCH, x, xb, n4, W1, pw1, W2, pw2, nb_cvt);
  binB2a_kernel<<<NBUCK, 256, 0, stream>>>(stage4, gcur, rowptr, dis, N, NBUCK, E);
  binB2b_kernel<<<NBUCK, 256, 0, stream>>>(stage4, rowptr, gcur, dis, ew, N);

  int pgrid = (N + 7) / 8;
  int pgrid64 = (N + 15) / 16;
  int ggrid = (N + 63) / 64;
  // ---- layer 1 + Horner-GEMM fused ----
  prop_kernel<<<pgrid, 256, 0, stream>>>(xb, nullptr, T1, rowptr, ew, dis, N);
  prop_kernel<<<pgrid, 256, 0, stream>>>(T1, xb,      T2, rowptr, ew, dis, N);
  prop_kernel<<<pgrid, 256, 0, stream>>>(T2, T1,      T3, rowptr, ew, dis, N);
  mfma_gemm_fused_kernel<<<ggrid, 128, 0, stream>>>(
      xb, T1, T2, T3, pw1, b1, pw2, CB, N);
  // ---- layer 2: Horner chain, 64-wide props ----
  prop64_kernel<false><<<pgrid64, 256, 0, stream>>>(C3, C2, I2, rowptr, ew, dis, nullptr, N);
  prop64_kernel<false><<<pgrid64, 256, 0, stream>>>(I2, C1, I3, rowptr, ew, dis, nullptr, N);
  prop64_kernel<true ><<<pgrid64, 256, 0, stream>>>(I3, C0, out, rowptr, ew, dis, b2, N);
}

// Round 16
// 268.148 us; speedup vs baseline: 1.0922x; 1.0922x over previous
//
#include <hip/hip_runtime.h>
#include <cstddef>
#include <cstdint>

#define N_IN  128
#define N_HID 128
#define N_OUT 64
#define CHUNK 4096        // edges per countbin block
#define BSPAN 512         // nodes per bucket
#define SCAP  12288       // stage capacity per bucket (mean 8192, max~8650 @ E=800k)

typedef unsigned short ushort;
typedef unsigned int uint;
using short8 = __attribute__((ext_vector_type(8))) short;
using f32x4  = __attribute__((ext_vector_type(4))) float;

__device__ __forceinline__ ushort f2b(float f) {
  uint u = __builtin_bit_cast(uint, f);
  uint r = (u + 0x7fffu + ((u >> 16) & 1u)) >> 16;   // RNE
  return (ushort)r;
}
__device__ __forceinline__ float b2f(ushort u) {
  return __builtin_bit_cast(float, ((uint)u) << 16);
}

// ================= fused bucket-bin + prep (no deg atomics — R13/R14) =================

__global__ __launch_bounds__(256) void countbin_kernel(
    const int* __restrict__ ei, int* __restrict__ gcur,
    uint* __restrict__ stage4, int E, int nbuck, int nch,
    const float* __restrict__ x, ushort* __restrict__ xb, int n4,
    const float* __restrict__ W1, ushort* __restrict__ pw1,
    const float* __restrict__ W2, ushort* __restrict__ pw2, int nb_cvt) {
  __shared__ int cnt[256], lstart[256], off[256], gbase[256];
  __shared__ uint stg[CHUNK];
  __shared__ unsigned char bos[CHUNK];
  int bid = blockIdx.x;
  if (bid >= nch) {
    int pb = bid - nch;
    if (pb < nb_cvt) {
      int i = pb * 256 + threadIdx.x;
      if (i >= n4) return;
      float4 v = reinterpret_cast<const float4*>(x)[i];
      ushort4 o;
      o.x = f2b(v.x); o.y = f2b(v.y); o.z = f2b(v.z); o.w = f2b(v.w);
      reinterpret_cast<ushort4*>(xb)[i] = o;
    } else if (pb < nb_cvt + 32) {
      constexpr int CT = N_HID / 16;
      int t = (pb - nb_cvt) * 256 + threadIdx.x;
      int lane = t & 63;
      int g = t >> 6;
      int ct = g % CT;
      int kk = (g / CT) % 4;
      int k  = g / (CT * 4);
      int col = ct * 16 + (lane & 15);
      int krow0 = kk * 32 + (lane >> 4) * 8;
      ushort* dst = pw1 + (size_t)t * 8;
      const float* src = W1 + ((size_t)k * 128 + krow0) * N_HID + col;
#pragma unroll
      for (int j = 0; j < 8; ++j) dst[j] = f2b(src[(size_t)j * N_HID]);
    } else {
      int t = (pb - nb_cvt - 32) * 256 + threadIdx.x;
      int lane = t & 63;
      int g = t >> 6;
      int ct = g & 15;
      int kk = g >> 4;
      int col = ct * 16 + (lane & 15);
      int kb = col >> 6;
      int cc = col & 63;
      int krow0 = kk * 32 + (lane >> 4) * 8;
      ushort* dst = pw2 + (size_t)t * 8;
#pragma unroll
      for (int j = 0; j < 8; ++j) {
        int r = krow0 + j;
        float w0 = W2[((size_t)0 * 128 + r) * 64 + cc];
        float w1 = W2[((size_t)1 * 128 + r) * 64 + cc];
        float w2 = W2[((size_t)2 * 128 + r) * 64 + cc];
        float w3 = W2[((size_t)3 * 128 + r) * 64 + cc];
        float v = (kb == 0) ? (w0 - w2)
                : (kb == 1) ? (w1 - 3.f * w3)
                : (kb == 2) ? (2.f * w2)
                            : (4.f * w3);
        dst[j] = f2b(v);
      }
    }
    return;
  }
  int e0 = bid * CHUNK;
  int tid = threadIdx.x;
  for (int i = tid; i < nbuck; i += 256) cnt[i] = 0;
  __syncthreads();
  int s[16], d[16];
#pragma unroll
  for (int j = 0; j < 16; ++j) {
    int e = e0 + tid + j * 256;
    s[j] = -1;
    if (e < E) {
      s[j] = ei[e];
      d[j] = ei[E + e];
      atomicAdd(&cnt[d[j] >> 9], 1);
    }
  }
  __syncthreads();
  if (tid == 0) {
    int run = 0;
    for (int b = 0; b < nbuck; ++b) { lstart[b] = run; run += cnt[b]; }
  }
  __syncthreads();
  for (int i = tid; i < nbuck; i += 256) off[i] = lstart[i];
  __syncthreads();
#pragma unroll
  for (int j = 0; j < 16; ++j) {
    if (s[j] >= 0) {
      int b = d[j] >> 9;
      int pos = atomicAdd(&off[b], 1);
      stg[pos] = (uint)s[j] | ((uint)(d[j] & (BSPAN - 1)) << 17);
      bos[pos] = (unsigned char)b;
    }
  }
  __syncthreads();
  for (int b = tid; b < nbuck; b += 256)
    if (cnt[b] > 0) gbase[b] = atomicAdd(&gcur[b], cnt[b]);
  __syncthreads();
  int total = min(CHUNK, E - e0);
  for (int i = tid; i < total; i += 256) {
    int b = bos[i];
    stage4[(size_t)b * SCAP + gbase[b] + (i - lstart[b])] = stg[i];
  }
}

// ================= binB2a: inline bucket-scan + per-bucket histogram -> rowptr, dis =================

__global__ __launch_bounds__(256) void binB2a_kernel(const uint* __restrict__ stage4,
                                                     const int* __restrict__ gcur,
                                                     int* __restrict__ rowptr,
                                                     float* __restrict__ dis,
                                                     int n, int nbuck, int E) {
  __shared__ int cnt[BSPAN];
  __shared__ int g[128];
  __shared__ int wsum[4];
  int b = blockIdx.x;
  int base = b << 9;
  int hi = min(base + BSPAN, n);
  int nb = hi - base;
  int tid = threadIdx.x;
  cnt[tid] = 0;
  cnt[tid + 256] = 0;
  for (int i = tid; i < nbuck; i += 256) g[i] = gcur[i];
  __syncthreads();
  int bb = 0;
  for (int i = 0; i < b; ++i) bb += g[i];   // LDS broadcast, <= 97 iters
  int cntb = g[b];
  const uint* st = stage4 + (size_t)b * SCAP;
  for (int t = tid; t < cntb; t += 256) atomicAdd(&cnt[st[t] >> 17], 1);
  __syncthreads();
  int c0 = cnt[2 * tid], c1 = cnt[2 * tid + 1];
  int pair = c0 + c1;
  int lane = tid & 63, wid = tid >> 6;
  int incl = pair;
#pragma unroll
  for (int off = 1; off < 64; off <<= 1) {
    int t = __shfl_up(incl, off, 64);
    if (lane >= off) incl += t;
  }
  if (lane == 63) wsum[wid] = incl;
  __syncthreads();
  int wbase = 0;
  for (int w = 0; w < wid; ++w) wbase += wsum[w];
  int e0 = bb + wbase + incl - pair;
  int l0 = 2 * tid, l1 = 2 * tid + 1;
  if (l0 < nb) {
    rowptr[base + l0] = e0;
    dis[base + l0] = (c0 > 0) ? rsqrtf((float)c0) : 0.f;
  }
  if (l1 < nb) {
    rowptr[base + l1] = e0 + c0;
    dis[base + l1] = (c1 > 0) ? rsqrtf((float)c1) : 0.f;
  }
  if (b == nbuck - 1 && tid == 0) rowptr[n] = E;
}

// ================= binB2b: fine scatter within bucket =================

__global__ __launch_bounds__(256) void binB2b_kernel(const uint* __restrict__ stage4,
                                                     const int* __restrict__ rowptr,
                                                     const int* __restrict__ gcur,
                                                     const float* __restrict__ dis,
                                                     int2* __restrict__ ew, int n) {
  __shared__ int cur[BSPAN];
  int b = blockIdx.x;
  int base = b << 9;
  int hi = min(base + BSPAN, n);
  for (int l = threadIdx.x; l < hi - base; l += 256) cur[l] = rowptr[base + l];
  __syncthreads();
  int cntb = gcur[b];
  const uint* st = stage4 + (size_t)b * SCAP;
  for (int t = threadIdx.x; t < cntb; t += 256) {
    uint v = st[t];
    int src = v & 0x1FFFF;
    int dl = v >> 17;
    int pos = atomicAdd(&cur[dl], 1);
    ew[pos] = make_int2(src, __builtin_bit_cast(int, dis[src]));
  }
}

// ================= sparse propagation, 128-wide (layer 1) =================
// 2 nodes/wave, 32 lanes x uint2; unroll 8 (unroll 16 measured WORSE, R11).

__global__ __launch_bounds__(256) void prop_kernel(
    const ushort* __restrict__ in, const ushort* __restrict__ sub,
    ushort* __restrict__ out,
    const int* __restrict__ rowptr, const int2* __restrict__ ew,
    const float* __restrict__ dis, int n) {
  int node = blockIdx.x * 8 + (threadIdx.x >> 5);
  if (node >= n) return;
  int hl = threadIdx.x & 31;
  int s = rowptr[node];
  int e = rowptr[node + 1];
  size_t ro = ((size_t)node << 7) + (hl << 2);
  uint2 sv = make_uint2(0u, 0u);
  if (sub != nullptr) sv = *reinterpret_cast<const uint2*>(sub + ro);
  float a0 = 0.f, a1 = 0.f, a2 = 0.f, a3 = 0.f;
  for (int i = s; i < e; i += 8) {
    int2 p[8];
#pragma unroll
    for (int j = 0; j < 8; ++j) {
      int idx = i + j;
      p[j] = ew[idx < e ? idx : e - 1];
    }
    uint2 v[8];
#pragma unroll
    for (int j = 0; j < 8; ++j)
      v[j] = *reinterpret_cast<const uint2*>(in + ((size_t)p[j].x << 7) + (hl << 2));
#pragma unroll
    for (int j = 0; j < 8; ++j) {
      float w = (i + j < e) ? __builtin_bit_cast(float, p[j].y) : 0.f;
      a0 = fmaf(w, b2f((ushort)v[j].x), a0);
      a1 = fmaf(w, b2f((ushort)(v[j].x >> 16)), a1);
      a2 = fmaf(w, b2f((ushort)v[j].y), a2);
      a3 = fmaf(w, b2f((ushort)(v[j].y >> 16)), a3);
    }
  }
  float sc = -dis[node];
  float r0, r1, r2, r3;
  if (sub != nullptr) {
    float t = 2.f * sc;
    r0 = fmaf(t, a0, -b2f((ushort)sv.x));
    r1 = fmaf(t, a1, -b2f((ushort)(sv.x >> 16)));
    r2 = fmaf(t, a2, -b2f((ushort)sv.y));
    r3 = fmaf(t, a3, -b2f((ushort)(sv.y >> 16)));
  } else {
    r0 = sc * a0; r1 = sc * a1; r2 = sc * a2; r3 = sc * a3;
  }
  uint2 o;
  o.x = (uint)f2b(r0) | ((uint)f2b(r1) << 16);
  o.y = (uint)f2b(r2) | ((uint)f2b(r3) << 16);
  *reinterpret_cast<uint2*>(out + ro) = o;
}

// ================= sparse propagation, 64-wide (layer-2 Horner chain) =================

template <bool F32OUT>
__global__ __launch_bounds__(256) void prop64_kernel(
    const ushort* __restrict__ in, const ushort* __restrict__ aux,
    void* __restrict__ outv,
    const int* __restrict__ rowptr, const int2* __restrict__ ew,
    const float* __restrict__ dis, const float* __restrict__ bias, int n) {
  int node = blockIdx.x * 16 + (threadIdx.x >> 4);
  if (node >= n) return;
  int fl = threadIdx.x & 15;
  int s = rowptr[node];
  int e = rowptr[node + 1];
  float a0 = 0.f, a1 = 0.f, a2 = 0.f, a3 = 0.f;
  for (int i = s; i < e; i += 8) {
    int2 p[8];
#pragma unroll
    for (int j = 0; j < 8; ++j) {
      int idx = i + j;
      p[j] = ew[idx < e ? idx : e - 1];
    }
    uint2 v[8];
#pragma unroll
    for (int j = 0; j < 8; ++j)
      v[j] = *reinterpret_cast<const uint2*>(in + ((size_t)p[j].x << 6) + (fl << 2));
#pragma unroll
    for (int j = 0; j < 8; ++j) {
      float w = (i + j < e) ? __builtin_bit_cast(float, p[j].y) : 0.f;
      a0 = fmaf(w, b2f((ushort)v[j].x), a0);
      a1 = fmaf(w, b2f((ushort)(v[j].x >> 16)), a1);
      a2 = fmaf(w, b2f((ushort)v[j].y), a2);
      a3 = fmaf(w, b2f((ushort)(v[j].y >> 16)), a3);
    }
  }
  float sc = -dis[node];
  size_t ro = ((size_t)node << 6) + (fl << 2);
  uint2 av = *reinterpret_cast<const uint2*>(aux + ro);
  float r0 = fmaf(sc, a0, b2f((ushort)av.x));
  float r1 = fmaf(sc, a1, b2f((ushort)(av.x >> 16)));
  float r2 = fmaf(sc, a2, b2f((ushort)av.y));
  float r3 = fmaf(sc, a3, b2f((ushort)(av.y >> 16)));
  if (F32OUT) {
    r0 += bias[fl << 2];
    r1 += bias[(fl << 2) + 1];
    r2 += bias[(fl << 2) + 2];
    r3 += bias[(fl << 2) + 3];
    float m = fmaxf(fmaxf(r0, r1), fmaxf(r2, r3));
#pragma unroll
    for (int o = 8; o > 0; o >>= 1) m = fmaxf(m, __shfl_xor(m, o, 64));
    float sum = __expf(r0 - m) + __expf(r1 - m) + __expf(r2 - m) + __expf(r3 - m);
#pragma unroll
    for (int o = 8; o > 0; o >>= 1) sum += __shfl_xor(sum, o, 64);
    float ls = logf(sum) + m;
    float4 o4 = make_float4(r0 - ls, r1 - ls, r2 - ls, r3 - ls);
    *reinterpret_cast<float4*>(reinterpret_cast<float*>(outv) + ro) = o4;
  } else {
    uint2 o;
    o.x = (uint)f2b(r0) | ((uint)f2b(r1) << 16);
    o.y = (uint)f2b(r2) | ((uint)f2b(r3) << 16);
    *reinterpret_cast<uint2*>(reinterpret_cast<ushort*>(outv) + ro) = o;
  }
}

// ================= MFMA GEMM, layer 1 (4 A's, FOUT=128, relu, bf16 out) =================

template <int FOUT, bool RELU>
__global__ __launch_bounds__(128) void mfma_gemm_kernel(
    const ushort* __restrict__ A0, const ushort* __restrict__ A1,
    const ushort* __restrict__ A2, const ushort* __restrict__ A3,
    const ushort* __restrict__ pw, const float* __restrict__ bias,
    ushort* __restrict__ outb, int n) {
  constexpr int CT = FOUT / 16;
  int wid = threadIdx.x >> 6;
  int lane = threadIdx.x & 63;
  int rbase = (blockIdx.x * 2 + wid) * 32;
  if (rbase >= n) return;                 // n % 16 == 0
  bool t1ok = (rbase + 16) < n;
  const ushort* Ap[4] = {A0, A1, A2, A3};
  f32x4 acc[2][CT];
#pragma unroll
  for (int t = 0; t < 2; ++t)
#pragma unroll
    for (int c = 0; c < CT; ++c) acc[t][c] = (f32x4){0.f, 0.f, 0.f, 0.f};
  size_t aoff = (size_t)(rbase + (lane & 15)) * 128 + (lane >> 4) * 8;
#pragma unroll
  for (int k = 0; k < 4; ++k) {
    const ushort* A = Ap[k] + aoff;
#pragma unroll
    for (int kk = 0; kk < 4; ++kk) {
      short8 a0 = *reinterpret_cast<const short8*>(A + kk * 32);
      short8 a1 = {};
      if (t1ok) a1 = *reinterpret_cast<const short8*>(A + 16 * 128 + kk * 32);
      const ushort* B = pw + ((size_t)((k * 4 + kk) * CT) * 64 + lane) * 8;
#pragma unroll
      for (int c = 0; c < CT; ++c) {
        short8 b = *reinterpret_cast<const short8*>(B + (size_t)c * 64 * 8);
        acc[0][c] = __builtin_amdgcn_mfma_f32_16x16x32_bf16(a0, b, acc[0][c], 0, 0, 0);
        acc[1][c] = __builtin_amdgcn_mfma_f32_16x16x32_bf16(a1, b, acc[1][c], 0, 0, 0);
      }
    }
  }
  int colb = lane & 15;
  int rsub = (lane >> 4) * 4;
#pragma unroll
  for (int t = 0; t < 2; ++t) {
    int row0 = rbase + t * 16;
    if (row0 >= n) continue;
#pragma unroll
    for (int c = 0; c < CT; ++c) {
      int col = c * 16 + colb;
      float bv = bias[col];
#pragma unroll
      for (int r = 0; r < 4; ++r) {
        int row = row0 + rsub + r;
        float v = acc[t][c][r] + bv;
        if (RELU) v = fmaxf(v, 0.f);
        outb[(size_t)row * FOUT + col] = f2b(v);
      }
    }
  }
}

// ================= MFMA GEMM, layer 2: C = H @ Wc, output 4 x [n,64] bf16 =================

__global__ __launch_bounds__(128) void mfma_gemmH_kernel(
    const ushort* __restrict__ A, const ushort* __restrict__ pw,
    ushort* __restrict__ C, int n) {
  constexpr int CT = 16;
  int wid = threadIdx.x >> 6;
  int lane = threadIdx.x & 63;
  int row0 = (blockIdx.x * 2 + wid) * 16;
  if (row0 >= n) return;
  f32x4 acc[CT];
#pragma unroll
  for (int c = 0; c < CT; ++c) acc[c] = (f32x4){0.f, 0.f, 0.f, 0.f};
  size_t aoff = (size_t)(row0 + (lane & 15)) * 128 + (lane >> 4) * 8;
#pragma unroll
  for (int kk = 0; kk < 4; ++kk) {
    short8 a = *reinterpret_cast<const short8*>(A + aoff + kk * 32);
    const ushort* B = pw + ((size_t)(kk * CT) * 64 + lane) * 8;
#pragma unroll
    for (int c = 0; c < CT; ++c) {
      short8 b = *reinterpret_cast<const short8*>(B + (size_t)c * 64 * 8);
      acc[c] = __builtin_amdgcn_mfma_f32_16x16x32_bf16(a, b, acc[c], 0, 0, 0);
    }
  }
  int colb = lane & 15;
  int rsub = (lane >> 4) * 4;
#pragma unroll
  for (int c = 0; c < CT; ++c) {
    int col = c * 16 + colb;
    int kb = col >> 6, wc = col & 63;
#pragma unroll
    for (int r = 0; r < 4; ++r) {
      int row = row0 + rsub + r;
      C[((size_t)kb * n + row) * 64 + wc] = f2b(acc[c][r]);
    }
  }
}

// ================= launcher =================

extern "C" void kernel_launch(void* const* d_in, const int* in_sizes, int n_in,
                              void* d_out, int out_size, void* d_ws, size_t ws_size,
                              hipStream_t stream) {
  const float* x  = (const float*)d_in[0];
  const int*   ei = (const int*)d_in[1];
  const float* W1 = (const float*)d_in[2];
  const float* b1 = (const float*)d_in[3];
  const float* W2 = (const float*)d_in[4];
  const float* b2 = (const float*)d_in[5];
  float* out = (float*)d_out;

  const int N = in_sizes[0] / N_IN;
  const int E = in_sizes[1] / 2;
  const int NBUCK = (N + BSPAN - 1) / BSPAN;
  const int NCH = (E + CHUNK - 1) / CHUNK;

  char* base = (char*)d_ws;
  size_t off = 0;
  auto alloc = [&](size_t bytes) -> void* {
    void* p = base + off;
    off = (off + bytes + 255) & ~(size_t)255;
    return p;
  };
  int*    gcur   = (int*)alloc((size_t)NBUCK * 4);
  int*    rowptr = (int*)alloc((size_t)(N + 1) * 4);
  uint*   stage4 = (uint*)alloc((size_t)NBUCK * SCAP * 4);
  int2*   ew     = (int2*)alloc((size_t)E * 8);
  float*  dis    = (float*)alloc((size_t)N * 4);
  size_t  fsz    = (size_t)N * N_IN * 2;
  ushort* S1 = (ushort*)alloc(fsz);
  ushort* S2 = (ushort*)alloc(fsz);
  ushort* S3 = (ushort*)alloc(fsz);
  ushort* S4 = (ushort*)alloc(fsz);
  ushort* S5 = (ushort*)alloc(fsz);
  ushort* CB = (ushort*)alloc((size_t)4 * N * N_OUT * 2);   // C0..C3, each [N,64]
  ushort* pw1 = (ushort*)alloc((size_t)4 * N_IN * N_HID * 2);
  ushort* pw2 = (ushort*)alloc((size_t)N_HID * 4 * N_OUT * 2);

  ushort *xb = S1, *T1 = S2, *T2 = S3, *T3 = S4, *H = S5;
  ushort *I2 = S2, *I3 = S3;
  ushort *C0 = CB, *C1 = CB + (size_t)N * 64, *C2 = CB + (size_t)2 * N * 64,
         *C3 = CB + (size_t)3 * N * 64;

  int n4 = N * N_IN / 4;
  int nb_cvt = (n4 + 255) / 256;

  hipMemsetAsync(gcur, 0, (size_t)NBUCK * 4, stream);
  countbin_kernel<<<NCH + nb_cvt + 32 + 16, 256, 0, stream>>>(
      ei, gcur, stage4, E, NBUCK, NCH, x, xb, n4, W1, pw1, W2, pw2, nb_cvt);
  binB2a_kernel<<<NBUCK, 256, 0, stream>>>(stage4, gcur, rowptr, dis, N, NBUCK, E);
  binB2b_kernel<<<NBUCK, 256, 0, stream>>>(stage4, rowptr, gcur, dis, ew, N);

  int pgrid = (N + 7) / 8;
  int pgrid64 = (N + 15) / 16;
  int ggrid = (N + 63) / 64;
  int ggrid2 = (N + 31) / 32;
  // ---- layer 1 ----
  prop_kernel<<<pgrid, 256, 0, stream>>>(xb, nullptr, T1, rowptr, ew, dis, N);
  prop_kernel<<<pgrid, 256, 0, stream>>>(T1, xb,      T2, rowptr, ew, dis, N);
  prop_kernel<<<pgrid, 256, 0, stream>>>(T2, T1,      T3, rowptr, ew, dis, N);
  mfma_gemm_kernel<N_HID, true><<<ggrid, 128, 0, stream>>>(
      xb, T1, T2, T3, pw1, b1, H, N);
  // ---- layer 2: Horner form, 64-wide props ----
  mfma_gemmH_kernel<<<ggrid2, 128, 0, stream>>>(H, pw2, CB, N);
  prop64_kernel<false><<<pgrid64, 256, 0, stream>>>(C3, C2, I2, rowptr, ew, dis, nullptr, N);
  prop64_kernel<false><<<pgrid64, 256, 0, stream>>>(I2, C1, I3, rowptr, ew, dis, nullptr, N);
  prop64_kernel<true ><<<pgrid64, 256, 0, stream>>>(I3, C0, out, rowptr, ew, dis, b2, N);
}